// Round 10
// baseline (184.980 us; speedup 1.0000x reference)
//
#include <hip/hip_runtime.h>
#include <hip/hip_bf16.h>

// GAT encoder, 2 layers. B=32, N=512, D=64, H=8, DK=8.
// Layer: xp = x@W -> s,t per head -> masked softmax over sources i per target j
//        -> out[j,h,:] = sum_i alpha * xp[i,h,:]  -> +bias, relu.
//
// Design ledger:
//  - Softmax shift m[j,h] = lrelu(smax[b,h] + t[j,h]) is a FIXED upper bound
//    (leaky_relu monotone) -> single pass over i, exp arg <= 0. (R2, verified)
//  - R6: global f32 atomicAdd dense combine = 133 MB HBM RMW. Never again.
//  - R7/R8: j-split + in-block combine; adj at 64B lines. aggr 48 us,
//    VALUBusy 55% -> DS-issue bound (4 DS per 8 FMA, 8x redundant xpl reads);
//    proj ~40 us by subtraction (2 blocks/CU latency-bound).
//  - R10 (this): aggr JV=4 (one xpl read feeds 32 FMA), rotation-swizzled
//    xpl slots (conflict-free distinct-lane b128), shfl iq-reduction;
//    proj 1024x16-row blocks, conflict-free b128 Wl reads, reg-prefetch.

namespace {

constexpr int NB = 32;      // batch
constexpr int NN = 512;     // nodes

__device__ __forceinline__ float lrelu(float x) { return fmaxf(x, 0.2f * x); }

// ---------------- Kernel A: xp = x@W ; s,t ; per-block s-max -> pmax --------
// grid: (B*N/16) = 1024 blocks, 256 threads. Thread (r=tid>>4, c4=tid&15)
// computes cols c4*4..c4*4+3 of its row.
__global__ __launch_bounds__(256) void gat_proj(
    const float* __restrict__ x,     // [B*N, 64]
    const float* __restrict__ W,     // [64, 64]
    const float* __restrict__ asrc,  // [8, 8]
    const float* __restrict__ adst,  // [8, 8]
    float* __restrict__ xp,          // [B*N, 64]
    float* __restrict__ s,           // [B*N, 8]
    float* __restrict__ t,           // [B*N, 8]
    float* __restrict__ pmax)        // [1024, 8] per-block s-max (dense)
{
    __shared__ float Wl[64 * 64];    // 16 KB
    __shared__ float xs[16 * 68];    // padded rows (68 = 17 float4) 4.25 KB
    __shared__ float red[16 * 8];
    const int tid = threadIdx.x;
    const int row0 = blockIdx.x * 16;

    // prefetch W (4 float4) + x (1 float4) into regs, then commit to LDS
    float4 wreg[4];
    const float4* W4 = reinterpret_cast<const float4*>(W);
    #pragma unroll
    for (int it = 0; it < 4; ++it) wreg[it] = W4[it * 256 + tid];
    const float4 xreg = reinterpret_cast<const float4*>(&x[row0 * 64])[tid];

    float4* Wl4 = reinterpret_cast<float4*>(Wl);
    #pragma unroll
    for (int it = 0; it < 4; ++it) Wl4[it * 256 + tid] = wreg[it];
    reinterpret_cast<float4*>(xs)[(tid >> 4) * 17 + (tid & 15)] = xreg;
    __syncthreads();

    const int r = tid >> 4;
    const int c4 = tid & 15;
    const int c0 = c4 * 4;
    const int h = c4 >> 1, half = c4 & 1;

    float acc[4] = {};
    #pragma unroll 4
    for (int k = 0; k < 64; ++k) {
        const float xv = xs[r * 68 + k];                 // 4-addr broadcast, conflict-free
        const float4 w4 = *reinterpret_cast<const float4*>(&Wl[k * 64 + c0]); // conflict-free b128
        acc[0] = fmaf(xv, w4.x, acc[0]);
        acc[1] = fmaf(xv, w4.y, acc[1]);
        acc[2] = fmaf(xv, w4.z, acc[2]);
        acc[3] = fmaf(xv, w4.w, acc[3]);
    }
    const int row = row0 + r;
    *reinterpret_cast<float4*>(&xp[row * 64 + c0]) =
        make_float4(acc[0], acc[1], acc[2], acc[3]);

    // s,t: 4-col partial dot + pair shuffle (lane bit0 == half)
    const float4 a4 = *reinterpret_cast<const float4*>(&asrc[h * 8 + half * 4]);
    const float4 d4 = *reinterpret_cast<const float4*>(&adst[h * 8 + half * 4]);
    float sp = acc[0] * a4.x + acc[1] * a4.y + acc[2] * a4.z + acc[3] * a4.w;
    float tp = acc[0] * d4.x + acc[1] * d4.y + acc[2] * d4.z + acc[3] * d4.w;
    sp += __shfl_xor(sp, 1);
    tp += __shfl_xor(tp, 1);
    if (half == 0) {
        s[row * 8 + h] = sp;
        t[row * 8 + h] = tp;
        red[r * 8 + h] = sp;
    }
    __syncthreads();
    if (tid < 8) {
        float mx = red[tid];
        #pragma unroll
        for (int rr = 1; rr < 16; ++rr) mx = fmaxf(mx, red[rr * 8 + tid]);
        pmax[blockIdx.x * 8 + tid] = mx;
    }
}

// ---------------- Kernel B: masked softmax over i + aggregation -------------
// grid: (N/16, B) = 1024 blocks, 512 threads.
// tid = jq(2) | h_hi(1) | iq(4) | h_lo(2): thread owns 4 j (jq*4..+3), head h,
// and i-subset {iq*2, iq*2+1} of each 32-chunk. One 32B xpl read feeds 32 FMA.
// iq lives in lane bits 2..5 -> final 16-way reduce via __shfl_xor(4..32).
__global__ __launch_bounds__(512) void gat_aggr(
    const float* __restrict__ xp,    // [B*N, 64]
    const float* __restrict__ s,     // [B*N, 8]
    const float* __restrict__ t,     // [B*N, 8]
    const float* __restrict__ pmax,  // [1024, 8] = [B][32][8]
    const int*   __restrict__ adj,   // [B, N, N]
    const float* __restrict__ bias,  // [64]
    float* __restrict__ outp)        // [B*N, 64]
{
    __shared__ float xpl[32 * 64];   // float4 slots rotated: ss=(slot+(ii>>1))&15 (8 KB)
    __shared__ float slt[8 * 33];    // s transposed [h][ii], pad 33 (2-way = free)
    __shared__ float ml[32 * 16];    // mask [ii][jc] (2 KB)

    const int tid = threadIdx.x;
    const int b = blockIdx.y;
    const int j0 = blockIdx.x * 16;
    const int h_lo = tid & 3;
    const int iq   = (tid >> 2) & 15;
    const int h_hi = (tid >> 6) & 1;
    const int jq   = tid >> 7;
    const int h = h_hi * 4 + h_lo;

    float sm = pmax[b * 256 + h];
    #pragma unroll
    for (int q = 1; q < 32; ++q) sm = fmaxf(sm, pmax[b * 256 + q * 8 + h]);

    float tv[4], m[4];
    #pragma unroll
    for (int jv = 0; jv < 4; ++jv) {
        tv[jv] = t[(b * NN + j0 + jq * 4 + jv) * 8 + h];
        m[jv] = lrelu(sm + tv[jv]);          // >= all e for this (j,h)
    }

    float acc[4][8] = {};
    float l[4] = {};

    // T14 prefetch registers
    float4 pa; float ps; int pmv;
    auto issue = [&](int i0) {
        pa = reinterpret_cast<const float4*>(&xp[(b * NN + i0) * 64])[tid];
        if (tid < 256) ps = s[(b * NN + i0) * 8 + tid];
        pmv = adj[(b * NN + i0 + (tid >> 4)) * NN + j0 + (tid & 15)];
    };
    issue(0);

    for (int c = 0; c < NN / 32; ++c) {
        const int i0 = c * 32;
        __syncthreads();                      // previous compute done; LDS free
        {   // commit prefetched chunk (swizzled xpl, transposed sl)
            const int ii = tid >> 4, slot = tid & 15;
            const int ss = (slot + (ii >> 1)) & 15;
            reinterpret_cast<float4*>(xpl)[ii * 16 + ss] = pa;
            if (tid < 256) slt[(tid & 7) * 33 + (tid >> 3)] = ps;
            ml[tid] = (pmv != 0 || (i0 + ii) == (j0 + slot)) ? 1.0f : 0.0f;
        }
        if (c + 1 < NN / 32) issue(i0 + 32);
        __syncthreads();                      // LDS visible

        #pragma unroll
        for (int u = 0; u < 2; ++u) {
            const int ii = iq * 2 + u;
            const float sv = slt[h * 33 + ii];
            const float4 mlv = *reinterpret_cast<const float4*>(&ml[ii * 16 + jq * 4]); // wave-broadcast
            const int s0 = (2 * h + iq) & 15;         // rotation: (slot + ii>>1)&15, ii>>1==iq
            const int s1 = (2 * h + 1 + iq) & 15;
            const float4 xa = reinterpret_cast<const float4*>(xpl)[ii * 16 + s0];
            const float4 xb = reinterpret_cast<const float4*>(xpl)[ii * 16 + s1];
            const float mla0 = mlv.x, mla1 = mlv.y, mla2 = mlv.z, mla3 = mlv.w;
            #pragma unroll
            for (int jv = 0; jv < 4; ++jv) {
                const float mlj = jv == 0 ? mla0 : jv == 1 ? mla1 : jv == 2 ? mla2 : mla3;
                const float z = sv + tv[jv];
                const float e = fmaxf(z, 0.2f * z);   // leaky_relu
                const float p = mlj * __expf(e - m[jv]);
                l[jv] += p;
                acc[jv][0] = fmaf(p, xa.x, acc[jv][0]);
                acc[jv][1] = fmaf(p, xa.y, acc[jv][1]);
                acc[jv][2] = fmaf(p, xa.z, acc[jv][2]);
                acc[jv][3] = fmaf(p, xa.w, acc[jv][3]);
                acc[jv][4] = fmaf(p, xb.x, acc[jv][4]);
                acc[jv][5] = fmaf(p, xb.y, acc[jv][5]);
                acc[jv][6] = fmaf(p, xb.z, acc[jv][6]);
                acc[jv][7] = fmaf(p, xb.w, acc[jv][7]);
            }
        }
    }

    // 16-way reduction over iq (lane bits 2..5) via shfl_xor; no LDS, no barrier
    #pragma unroll
    for (int msk = 4; msk <= 32; msk <<= 1) {
        #pragma unroll
        for (int jv = 0; jv < 4; ++jv) {
            #pragma unroll
            for (int d = 0; d < 8; ++d) acc[jv][d] += __shfl_xor(acc[jv][d], msk);
            l[jv] += __shfl_xor(l[jv], msk);
        }
    }

    if (iq == 0) {
        const float4 b0 = *reinterpret_cast<const float4*>(&bias[h * 8]);
        const float4 b1 = *reinterpret_cast<const float4*>(&bias[h * 8 + 4]);
        #pragma unroll
        for (int jv = 0; jv < 4; ++jv) {
            const float rec = 1.0f / l[jv];
            const int row = b * NN + j0 + jq * 4 + jv;
            float4 o0, o1;
            o0.x = fmaxf(fmaf(acc[jv][0], rec, b0.x), 0.0f);
            o0.y = fmaxf(fmaf(acc[jv][1], rec, b0.y), 0.0f);
            o0.z = fmaxf(fmaf(acc[jv][2], rec, b0.z), 0.0f);
            o0.w = fmaxf(fmaf(acc[jv][3], rec, b0.w), 0.0f);
            o1.x = fmaxf(fmaf(acc[jv][4], rec, b1.x), 0.0f);
            o1.y = fmaxf(fmaf(acc[jv][5], rec, b1.y), 0.0f);
            o1.z = fmaxf(fmaf(acc[jv][6], rec, b1.z), 0.0f);
            o1.w = fmaxf(fmaf(acc[jv][7], rec, b1.w), 0.0f);
            float4* po = reinterpret_cast<float4*>(&outp[row * 64 + h * 8]);
            po[0] = o0;
            po[1] = o1;
        }
    }
}

} // namespace

extern "C" void kernel_launch(void* const* d_in, const int* in_sizes, int n_in,
                              void* d_out, int out_size, void* d_ws, size_t ws_size,
                              hipStream_t stream) {
    const float* n_in0  = (const float*)d_in[0];   // [B,N,64]
    const int*   adj    = (const int*)d_in[1];     // [B,N,N]
    const float* W1     = (const float*)d_in[2];
    const float* asrc1  = (const float*)d_in[3];
    const float* adst1  = (const float*)d_in[4];
    const float* b1     = (const float*)d_in[5];
    const float* W2     = (const float*)d_in[6];
    const float* asrc2  = (const float*)d_in[7];
    const float* adst2  = (const float*)d_in[8];
    const float* b2     = (const float*)d_in[9];

    float* ws = (float*)d_ws;
    float* xp   = ws;                    // 1048576 floats
    float* s    = xp + 1048576;          // 131072
    float* t    = s + 131072;            // 131072
    float* x2   = t + 131072;            // 1048576
    float* pmax = x2 + 1048576;          // 8192 (dense-written every call)

    const dim3 gProj(NB * NN / 16);      // 1024 blocks x 16 rows
    const dim3 gAggr(NN / 16, NB);       // 1024 blocks

    // Layer 1
    gat_proj<<<gProj, 256, 0, stream>>>(n_in0, W1, asrc1, adst1, xp, s, t, pmax);
    gat_aggr<<<gAggr, 512, 0, stream>>>(xp, s, t, pmax, adj, b1, x2);
    // Layer 2
    gat_proj<<<gProj, 256, 0, stream>>>(x2, W2, asrc2, adst2, xp, s, t, pmax);
    gat_aggr<<<gAggr, 512, 0, stream>>>(xp, s, t, pmax, adj, b2, (float*)d_out);
}